// Round 22
// baseline (656.310 us; speedup 1.0000x reference)
//
#include <hip/hip_runtime.h>
#include <stdint.h>

#define KCODES 8192
#define DIM 256
#define BN 128              // rescan col tile
#define NKT (KCODES / BN)   // 64 tiles
#define NSTEP (NKT * 4)     // 256 steps of 64 d

typedef _Float16 h16;
typedef __attribute__((ext_vector_type(8))) _Float16 f16x8;
typedef __attribute__((ext_vector_type(4))) float f32x4;

__device__ __forceinline__ void split8(const float* __restrict__ x, f16x8& h, f16x8& l) {
    #pragma unroll
    for (int i = 0; i < 8; ++i) {
        float v = x[i];
        _Float16 hv = (_Float16)v;          // RNE
        h[i] = hv;
        l[i] = (_Float16)(v - (float)hv);   // exact residual in f32, RNE to f16
    }
}

__device__ __forceinline__ unsigned int ford(float f) {   // monotone float->uint
    unsigned int b = __float_as_uint(f);
    return (b & 0x80000000u) ? ~b : (b | 0x80000000u);
}

// ---- ws layout (bytes); ws >= 8.4 MB (proven R5-R21) ----
#define WS_C2H   0u          // 8192 f32
#define WS_LC    32768u      // 8192 f32 ||rho_c||
#define WS_CN    65536u      // 8192 f32 ||c||
#define WS_CNT   98304u      // int cnt
#define WS_LIST  98560u
#define WS_KEYS  917504u
#define WS_BPH   2097152u    // 4 MB h-only lane-ordered fragment image

// ---------------- fused prep: pack frag-image + c2h/lc/cn --------------------
// Image (proven R18-R21): [halfstep = (kt*4+cp)*2 + h][frag = n*2+j][lane][16B],
// 1 KB frags, 8 per halfstep. Frag lane l = g*16+c15 holds h-f16 of code
// kt*128 + h*64 + n*16 + c15, d = cp*64 + j*32 + g*8 .. +7 (A/B same map).
__global__ __launch_bounds__(256) void prep_kernel(const float* __restrict__ cb,
                                                   h16* __restrict__ Bp,
                                                   float* __restrict__ c2h,
                                                   float* __restrict__ lc,
                                                   float* __restrict__ cn) {
    const int tid = blockIdx.x * 256 + threadIdx.x;   // 8192*32
    const int code = tid >> 5;
    const int grp = tid & 31;                         // 8-d group
    float x[8];
    *(float4*)&x[0] = *(const float4*)(cb + (size_t)code * DIM + grp * 8);
    *(float4*)&x[4] = *(const float4*)(cb + (size_t)code * DIM + grp * 8 + 4);
    f16x8 hh;
    float s = 0.f, sr = 0.f;
    #pragma unroll
    for (int i = 0; i < 8; ++i) {
        float v = x[i];
        _Float16 hv = (_Float16)v;
        hh[i] = hv;
        s += v * v;
        float rho = v - (float)hv;
        sr += rho * rho;
    }
    const int kt = code >> 7, c = code & 127;
    const int h = c >> 6, cl = c & 63;
    const int n = cl >> 4, c15 = cl & 15;
    const int cp = grp >> 3, j = (grp >> 2) & 1, g = grp & 3;
    const int lane = g * 16 + c15;
    const size_t off = (((size_t)((kt * 4 + cp) * 2 + h) * 8) + (n * 2 + j)) * 512 + lane * 8;
    *(f16x8*)(Bp + off) = hh;

    #pragma unroll
    for (int o = 16; o > 0; o >>= 1) { s += __shfl_xor(s, o); sr += __shfl_xor(sr, o); }
    if (grp == 0) {
        c2h[code] = 0.5f * s;
        cn[code] = sqrtf(s);
        lc[code] = sqrtf(sr);
    }
}

// ---------------- pass 1 + fused resolve -------------------------------------
// REGISTER-DIRECT B: the lane-ordered image means each lane consumes exactly
// the 16 B it would stage -> the LDS hop is pure pass-through. Load fragments
// straight into breg[2][8] (parity double-buffer, static via unrolled cp).
// Compiler inserts counted vmcnt before next step's MFMAs (one full step of
// load flight). No barriers, no hot-loop LDS, no asm waits.
__global__ __launch_bounds__(256) void vq_pass1(
    const float* __restrict__ rep, const float* __restrict__ cb,
    const h16* __restrict__ Bp, const float* __restrict__ c2h,
    const float* __restrict__ lcA, const float* __restrict__ cnA,
    int* __restrict__ out, int* __restrict__ cnt, int* __restrict__ list) {

    __shared__ float sv1[128];           // [row 0..63][half 0..1]
    __shared__ int si1[128];
    __shared__ float sv2[128];
    __shared__ int cand_s[64];
    __shared__ float thr_s[64];

    const int t = threadIdx.x;
    const int lane = t & 63;
    const int c15 = lane & 15;
    const int g = lane >> 4;
    const int w = t >> 6;                 // wave 0..3
    const int rh = w >> 1;                // row half 0/1
    const int h = w & 1;                  // col half 0/1
    const int brow = blockIdx.x * 64;

    // ---- A: h fragments + norms; row-correct copies via shfl ----
    f16x8 ah[2][8];
    float hnr[2][4], rnr[2][4];
    #pragma unroll
    for (int m = 0; m < 2; ++m) {
        const float* ar = rep + (size_t)(brow + rh * 32 + m * 16 + c15) * DIM + g * 8;
        float hs = 0.f, rs = 0.f;
        #pragma unroll
        for (int ch = 0; ch < 8; ++ch) {
            float x[8];
            *(float4*)&x[0] = *(const float4*)(ar + ch * 32);
            *(float4*)&x[4] = *(const float4*)(ar + ch * 32 + 4);
            #pragma unroll
            for (int i = 0; i < 8; ++i) {
                _Float16 hv = (_Float16)x[i];
                ah[m][ch][i] = hv;
                float hf = (float)hv;
                hs += hf * hf;
                float rho = x[i] - hf;
                rs += rho * rho;
            }
        }
        hs += __shfl_xor(hs, 16); hs += __shfl_xor(hs, 32);
        rs += __shfl_xor(rs, 16); rs += __shfl_xor(rs, 32);
        float hn = sqrtf(hs), rn = sqrtf(rs);
        #pragma unroll
        for (int r = 0; r < 4; ++r) {     // C/D rows for this lane are g*4+r
            hnr[m][r] = __shfl(hn, g * 4 + r);
            rnr[m][r] = __shfl(rn, g * 4 + r);
        }
    }

    f32x4 acc[2][4];
    f16x8 breg[2][8];                     // [parity][frag], static post-unroll
    float u1v[2][4], u2v[2][4], Dl[4], Dc[4], D2[4];
    int u1i[2][4];
    #pragma unroll
    for (int m = 0; m < 2; ++m)
        #pragma unroll
        for (int n = 0; n < 4; ++n) {
            #pragma unroll
            for (int r = 0; r < 4; ++r) acc[m][n][r] = 0.f;
            u1v[m][n] = -3.4e38f; u2v[m][n] = -3.4e38f; u1i[m][n] = 0;
        }

    // prologue: step 0 fragments -> breg[0]
    {
        const h16* src = Bp + (size_t)h * 4096 + lane * 8;
        #pragma unroll
        for (int f = 0; f < 8; ++f)
            breg[0][f] = *(const f16x8*)(src + f * 512);
    }

    #pragma unroll 1
    for (int kt = 0; kt < NKT; ++kt) {
        const int ktbase = kt * BN;
        #pragma unroll
        for (int cp = 0; cp < 4; ++cp) {            // step S = kt*4+cp
            const int S = kt * 4 + cp;
            const int p = cp & 1;                   // parity == S&1 (static)
            if (cp == 0) {                          // per-kt bound constants
                #pragma unroll
                for (int n = 0; n < 4; ++n) {
                    const int col = ktbase + h * 64 + n * 16 + c15;
                    Dl[n] = lcA[col];
                    Dc[n] = cnA[col];
                    D2[n] = 0.012f - c2h[col];
                }
            }
            if (S + 1 < NSTEP) {                    // issue next step's loads
                const h16* src = Bp + (size_t)((S + 1) * 2 + h) * 4096 + lane * 8;
                #pragma unroll
                for (int f = 0; f < 8; ++f)
                    breg[p ^ 1][f] = *(const f16x8*)(src + f * 512);
            }

            // 16 MFMA from breg[p] (loaded last step; full step of flight)
            #pragma unroll
            for (int j = 0; j < 2; ++j) {
                const int ch = cp * 2 + j;          // d-chunk 0..7, static
                #pragma unroll
                for (int n = 0; n < 4; ++n)
                    #pragma unroll
                    for (int m = 0; m < 2; ++m)
                        acc[m][n] = __builtin_amdgcn_mfma_f32_16x16x32_f16(ah[m][ch], breg[p][n * 2 + j], acc[m][n], 0, 0, 0);
            }

            if (cp == 3) {   // per-kt epilogue: u = acc + row-code bound; top-2
                #pragma unroll
                for (int n = 0; n < 4; ++n) {
                    const int col = ktbase + h * 64 + n * 16 + c15;
                    #pragma unroll
                    for (int m = 0; m < 2; ++m)
                        #pragma unroll
                        for (int r = 0; r < 4; ++r) {
                            float u = fmaf(hnr[m][r], Dl[n],
                                      fmaf(rnr[m][r], Dc[n], acc[m][n][r] + D2[n]));
                            if (u > u1v[m][r]) { u2v[m][r] = u1v[m][r]; u1v[m][r] = u; u1i[m][r] = col; }
                            else if (u > u2v[m][r]) u2v[m][r] = u;
                            acc[m][n][r] = 0.f;
                        }
                }
            }
        }
    }

    // ---- merge top-2 across 16 c15-lanes, then across col-half waves ----
    #pragma unroll
    for (int m = 0; m < 2; ++m)
        #pragma unroll
        for (int r = 0; r < 4; ++r) {
            float a1 = u1v[m][r], a2 = u2v[m][r];
            int a1i = u1i[m][r];
            #pragma unroll
            for (int mask = 1; mask <= 8; mask <<= 1) {
                float b1 = __shfl_xor(a1, mask);
                int b1i = __shfl_xor(a1i, mask);
                float b2 = __shfl_xor(a2, mask);
                if (b1 > a1) { a2 = fmaxf(a1, b2); a1 = b1; a1i = b1i; }
                else         { a2 = fmaxf(b1, a2); }
            }
            if (c15 == 0) {
                const int rl = rh * 32 + m * 16 + g * 4 + r;   // 0..63
                sv1[rl * 2 + h] = a1;
                si1[rl * 2 + h] = a1i;
                sv2[rl * 2 + h] = a2;
            }
        }
    __syncthreads();
    if (t < 64) {
        float a1 = sv1[t * 2], a2 = sv2[t * 2];
        int a1i = si1[t * 2];
        float b1 = sv1[t * 2 + 1], b2 = sv2[t * 2 + 1];
        int b1i = si1[t * 2 + 1];
        float u1, u2; int u1idx;
        if (b1 > a1) { u1 = b1; u1idx = b1i; u2 = fmaxf(a1, b2); }
        else         { u1 = a1; u1idx = a1i; u2 = fmaxf(b1, a2); }
        cand_s[t] = u1idx;
        thr_s[t] = u2;
        out[brow + t] = u1idx;            // provisional; rescan may overwrite
    }
    __syncthreads();

    // ---- fused resolve: wave w exactly rescores rows w*16 .. w*16+15 ----
    #pragma unroll 1
    for (int i = 0; i < 16; ++i) {
        const int rl = w * 16 + i;
        const int grow = brow + rl;
        const int ci = cand_s[rl];
        const float4 rv = *(const float4*)(rep + (size_t)grow * DIM + lane * 4);
        const float4 cv = *(const float4*)(cb + (size_t)ci * DIM + lane * 4);
        float p = rv.x * cv.x + rv.y * cv.y + rv.z * cv.z + rv.w * cv.w;
        #pragma unroll
        for (int off = 32; off > 0; off >>= 1) p += __shfl_down(p, off);
        if (lane == 0) {
            float sex = p - c2h[ci];
            if (!(sex > thr_s[rl])) {     // not provably optimal -> rescan
                int pos = atomicAdd(cnt, 1);
                list[pos] = grow;
            }
        }
    }
}

// ---------------- rescan: (row-group x kt) parallel exact 4-pass tiles -------
__global__ __launch_bounds__(256) void rescan_kernel(
    const float* __restrict__ rep, const float* __restrict__ cb,
    const float* __restrict__ c2h, const int* __restrict__ cnt_p,
    const int* __restrict__ list, unsigned long long* __restrict__ keys) {

    const int cnt = *cnt_p;
    const int base = blockIdx.x * 64;
    if (base >= cnt) return;
    const int nrows = min(64, cnt - base);
    const int ktbase = (int)blockIdx.y * BN;

    __shared__ __align__(16) h16 lds[2][BN * 64];
    const int t = threadIdx.x;
    const int lane = t & 63;
    const int w = t >> 6;
    const int c15 = lane & 15;
    const int g = lane >> 4;
    const int wrow = w * 16;

    const int aslot = wrow + c15;
    const int grow = list[base + (aslot < nrows ? aslot : 0)];
    f16x8 ah[8], al[8];
    {
        const float* ar = rep + (size_t)grow * DIM + g * 8;
        #pragma unroll
        for (int ch = 0; ch < 8; ++ch) {
            float x[8];
            *(float4*)&x[0] = *(const float4*)(ar + ch * 32);
            *(float4*)&x[4] = *(const float4*)(ar + ch * 32 + 4);
            split8(x, ah[ch], al[ch]);
        }
    }
    f32x4 acc[8];
    float cc[8];
    #pragma unroll
    for (int n = 0; n < 8; ++n) {
        #pragma unroll
        for (int r = 0; r < 4; ++r) acc[n][r] = 0.f;
        cc[n] = c2h[ktbase + n * 16 + c15];
    }

    const int scol = t >> 1;
    const int dslot = t & 1;
    float breg[16];
    auto loadB = [&](int ch) {
        const float* src = cb + (size_t)(ktbase + scol) * DIM + ch * 32 + dslot * 16;
        #pragma unroll
        for (int i = 0; i < 4; ++i) *(float4*)&breg[i * 4] = *(const float4*)(src + i * 4);
    };
    auto writeB = [&](int buf) {
        #pragma unroll
        for (int half = 0; half < 2; ++half) {
            f16x8 hh, ll;
            split8(&breg[half * 8], hh, ll);
            const int s = dslot * 2 + half;
            *(f16x8*)&lds[buf][scol * 64 + ((s ^ (scol & 7)) << 3)] = hh;
            *(f16x8*)&lds[buf][scol * 64 + (((s + 4) ^ (scol & 7)) << 3)] = ll;
        }
    };

    loadB(0);
    writeB(0);
    loadB(1);
    __syncthreads();

    #pragma unroll
    for (int chunk = 0; chunk < 8; ++chunk) {
        const int buf = chunk & 1;
        if (chunk != 7) writeB(buf ^ 1);
        if (chunk <= 5) loadB(chunk + 2);
        #pragma unroll
        for (int n = 0; n < 8; ++n) {
            const int bb2 = (n * 16 + c15) * 64;
            f16x8 bh = *(const f16x8*)&lds[buf][bb2 + ((g ^ (lane & 7)) << 3)];
            f16x8 bl = *(const f16x8*)&lds[buf][bb2 + (((4 + g) ^ (lane & 7)) << 3)];
            acc[n] = __builtin_amdgcn_mfma_f32_16x16x32_f16(ah[chunk], bh, acc[n], 0, 0, 0);
            acc[n] = __builtin_amdgcn_mfma_f32_16x16x32_f16(ah[chunk], bl, acc[n], 0, 0, 0);
            acc[n] = __builtin_amdgcn_mfma_f32_16x16x32_f16(al[chunk], bh, acc[n], 0, 0, 0);
            acc[n] = __builtin_amdgcn_mfma_f32_16x16x32_f16(al[chunk], bl, acc[n], 0, 0, 0);
        }
        __syncthreads();
    }

    #pragma unroll
    for (int r = 0; r < 4; ++r) {
        float bv = -3.4e38f;
        int bi = 0;
        #pragma unroll
        for (int n = 0; n < 8; ++n) {
            float s2 = acc[n][r] - cc[n];
            const int col = ktbase + n * 16 + c15;
            if (s2 > bv) { bv = s2; bi = col; }
        }
        #pragma unroll
        for (int mask = 1; mask <= 8; mask <<= 1) {
            float ov = __shfl_xor(bv, mask);
            int oi = __shfl_xor(bi, mask);
            if (ov > bv || (ov == bv && oi < bi)) { bv = ov; bi = oi; }
        }
        const int oslot = wrow + g * 4 + r;
        if (c15 == 0 && oslot < nrows) {
            unsigned long long key =
                ((unsigned long long)ford(bv) << 32) | (unsigned int)(~(unsigned int)bi);
            atomicMax(&keys[list[base + oslot]], key);
        }
    }
}

// ---------------- writeback listed rows from merged keys ----------------
__global__ __launch_bounds__(256) void writeback_kernel(
    const int* __restrict__ cnt_p, const int* __restrict__ list,
    const unsigned long long* __restrict__ keys, int* __restrict__ out) {
    int i = blockIdx.x * 256 + threadIdx.x;
    if (i >= *cnt_p) return;
    int row = list[i];
    out[row] = (int)(~(unsigned int)(keys[row] & 0xFFFFFFFFull));
}

extern "C" void kernel_launch(void* const* d_in, const int* in_sizes, int n_in,
                              void* d_out, int out_size, void* d_ws, size_t ws_size,
                              hipStream_t stream) {
    const float* rep = (const float*)d_in[0];
    const float* cb = (const float*)d_in[1];
    const int N = in_sizes[0] / DIM;   // 65536
    const int K = in_sizes[1] / DIM;   // 8192
    (void)K;
    char* ws = (char*)d_ws;
    float* c2h = (float*)(ws + WS_C2H);
    float* lc  = (float*)(ws + WS_LC);
    float* cn  = (float*)(ws + WS_CN);
    int* cnt   = (int*)(ws + WS_CNT);
    int* list  = (int*)(ws + WS_LIST);
    unsigned long long* keys = (unsigned long long*)(ws + WS_KEYS);
    h16* Bph   = (h16*)(ws + WS_BPH);
    int* out = (int*)d_out;

    hipMemsetAsync(ws + WS_CNT, 0, 64, stream);
    hipMemsetAsync(keys, 0, (size_t)N * sizeof(unsigned long long), stream);
    prep_kernel<<<dim3(KCODES * 32 / 256), dim3(256), 0, stream>>>(cb, Bph, c2h, lc, cn);
    vq_pass1<<<dim3(N / 64), dim3(256), 0, stream>>>(rep, cb, Bph, c2h, lc, cn, out, cnt, list);
    rescan_kernel<<<dim3(N / 64, NKT), dim3(256), 0, stream>>>(rep, cb, c2h, cnt, list, keys);
    writeback_kernel<<<dim3(N / 256), dim3(256), 0, stream>>>(cnt, list, keys, out);
}

// Round 23
// 520.300 us; speedup vs baseline: 1.2614x; 1.2614x over previous
//
#include <hip/hip_runtime.h>
#include <stdint.h>

#define KCODES 8192
#define DIM 256
#define BN 128              // rescan col tile
#define NKT (KCODES / BN)   // 64 tiles
#define NSTEP (NKT * 4)     // 256 steps of 64 d

typedef _Float16 h16;
typedef __attribute__((ext_vector_type(8))) _Float16 f16x8;
typedef __attribute__((ext_vector_type(4))) float f32x4;

__device__ __forceinline__ void split8(const float* __restrict__ x, f16x8& h, f16x8& l) {
    #pragma unroll
    for (int i = 0; i < 8; ++i) {
        float v = x[i];
        _Float16 hv = (_Float16)v;          // RNE
        h[i] = hv;
        l[i] = (_Float16)(v - (float)hv);   // exact residual in f32, RNE to f16
    }
}

__device__ __forceinline__ unsigned int ford(float f) {   // monotone float->uint
    unsigned int b = __float_as_uint(f);
    return (b & 0x80000000u) ? ~b : (b | 0x80000000u);
}

// ---- ws layout (bytes); ws >= 8.4 MB (proven R5-R22) ----
#define WS_C2H   0u          // 8192 f32
#define WS_LC    32768u      // 8192 f32 ||rho_c||
#define WS_CN    65536u      // 8192 f32 ||c||
#define WS_CNT   98304u      // int cnt
#define WS_LIST  98560u
#define WS_KEYS  917504u
#define WS_BPH   2097152u    // 4 MB h-only lane-ordered fragment image

// ---------------- fused prep: pack frag-image + c2h/lc/cn --------------------
// Image (proven R18-R21): [halfstep = (kt*4+cp)*2 + h][frag = n*2+j][lane][16B],
// 1 KB frags, 8 per halfstep. Frag lane l = g*16+c15 holds h-f16 of code
// kt*128 + h*64 + n*16 + c15, d = cp*64 + j*32 + g*8 .. +7 (A/B same map).
__global__ __launch_bounds__(256) void prep_kernel(const float* __restrict__ cb,
                                                   h16* __restrict__ Bp,
                                                   float* __restrict__ c2h,
                                                   float* __restrict__ lc,
                                                   float* __restrict__ cn) {
    const int tid = blockIdx.x * 256 + threadIdx.x;   // 8192*32
    const int code = tid >> 5;
    const int grp = tid & 31;                         // 8-d group
    float x[8];
    *(float4*)&x[0] = *(const float4*)(cb + (size_t)code * DIM + grp * 8);
    *(float4*)&x[4] = *(const float4*)(cb + (size_t)code * DIM + grp * 8 + 4);
    f16x8 hh;
    float s = 0.f, sr = 0.f;
    #pragma unroll
    for (int i = 0; i < 8; ++i) {
        float v = x[i];
        _Float16 hv = (_Float16)v;
        hh[i] = hv;
        s += v * v;
        float rho = v - (float)hv;
        sr += rho * rho;
    }
    const int kt = code >> 7, c = code & 127;
    const int h = c >> 6, cl = c & 63;
    const int n = cl >> 4, c15 = cl & 15;
    const int cp = grp >> 3, j = (grp >> 2) & 1, g = grp & 3;
    const int lane = g * 16 + c15;
    const size_t off = (((size_t)((kt * 4 + cp) * 2 + h) * 8) + (n * 2 + j)) * 512 + lane * 8;
    *(f16x8*)(Bp + off) = hh;

    #pragma unroll
    for (int o = 16; o > 0; o >>= 1) { s += __shfl_xor(s, o); sr += __shfl_xor(sr, o); }
    if (grp == 0) {
        c2h[code] = 0.5f * s;
        cn[code] = sqrtf(s);
        lc[code] = sqrtf(sr);
    }
}

// ---------------- pass 1 + fused resolve -------------------------------------
// R21 final form: barrier-free hot loop, wave-private 2x8KB LDS ring via
// global_load_lds (the LDS hop is a decoupling buffer - R22 proved register-
// direct is slower), counted vmcnt ledger (vmcnt(20) at cp==0 keeps the 12
// bound loads + next staging in flight), wave tile 32x64 (m2 x n4 of
// 16x16x32), per-code row-correct Cauchy-Schwarz bound, fused exact resolve.
__global__ __launch_bounds__(256) void vq_pass1(
    const float* __restrict__ rep, const float* __restrict__ cb,
    const h16* __restrict__ Bp, const float* __restrict__ c2h,
    const float* __restrict__ lcA, const float* __restrict__ cnA,
    int* __restrict__ out, int* __restrict__ cnt, int* __restrict__ list) {

    __shared__ __align__(16) h16 lds[4][2][8][512];   // [wave][buf][frag][1KB] = 64 KB

    const int t = threadIdx.x;
    const int lane = t & 63;
    const int c15 = lane & 15;
    const int g = lane >> 4;
    const int w = t >> 6;                 // wave 0..3
    const int rh = w >> 1;                // row half 0/1
    const int h = w & 1;                  // col half 0/1
    const int brow = blockIdx.x * 64;

    // ---- A: h fragments + norms; row-correct copies via shfl ----
    f16x8 ah[2][8];
    float hnr[2][4], rnr[2][4];
    #pragma unroll
    for (int m = 0; m < 2; ++m) {
        const float* ar = rep + (size_t)(brow + rh * 32 + m * 16 + c15) * DIM + g * 8;
        float hs = 0.f, rs = 0.f;
        #pragma unroll
        for (int ch = 0; ch < 8; ++ch) {
            float x[8];
            *(float4*)&x[0] = *(const float4*)(ar + ch * 32);
            *(float4*)&x[4] = *(const float4*)(ar + ch * 32 + 4);
            #pragma unroll
            for (int i = 0; i < 8; ++i) {
                _Float16 hv = (_Float16)x[i];
                ah[m][ch][i] = hv;
                float hf = (float)hv;
                hs += hf * hf;
                float rho = x[i] - hf;
                rs += rho * rho;
            }
        }
        hs += __shfl_xor(hs, 16); hs += __shfl_xor(hs, 32);
        rs += __shfl_xor(rs, 16); rs += __shfl_xor(rs, 32);
        float hn = sqrtf(hs), rn = sqrtf(rs);
        #pragma unroll
        for (int r = 0; r < 4; ++r) {     // C/D rows for this lane are g*4+r
            hnr[m][r] = __shfl(hn, g * 4 + r);
            rnr[m][r] = __shfl(rn, g * 4 + r);
        }
    }

    f32x4 acc[2][4];
    float u1v[2][4], u2v[2][4], Dl[4], Dc[4], D2[4];
    int u1i[2][4];
    #pragma unroll
    for (int m = 0; m < 2; ++m)
        #pragma unroll
        for (int n = 0; n < 4; ++n) {
            #pragma unroll
            for (int r = 0; r < 4; ++r) acc[m][n][r] = 0.f;
            u1v[m][n] = -3.4e38f; u2v[m][n] = -3.4e38f; u1i[m][n] = 0;
        }

    // wave-private staging: 8 x 1 KB lane-linear chunks per step
    auto issueStep = [&](int S, int buf) {
        const h16* src = Bp + ((size_t)(S * 2 + h) * 8) * 512 + lane * 8;
        #pragma unroll
        for (int f = 0; f < 8; ++f)
            __builtin_amdgcn_global_load_lds(
                (const __attribute__((address_space(1))) uint32_t*)(src + f * 512),
                (__attribute__((address_space(3))) uint32_t*)(&lds[w][buf][f][lane * 8]),
                16, 0, 0);
    };

    asm volatile("s_waitcnt vmcnt(0)" ::: "memory");   // drain A loads
    issueStep(0, 0);

    #pragma unroll 1
    for (int kt = 0; kt < NKT; ++kt) {
        const int ktbase = kt * BN;
        #pragma unroll
        for (int cp = 0; cp < 4; ++cp) {            // step S = kt*4+cp
            const int S = kt * 4 + cp;
            const int cur = cp & 1;                 // ring parity (4 even)
            if (cp == 0) {                          // per-kt bound constants
                #pragma unroll
                for (int n = 0; n < 4; ++n) {
                    const int col = ktbase + h * 64 + n * 16 + c15;
                    Dl[n] = lcA[col];
                    Dc[n] = cnA[col];
                    D2[n] = 0.012f - c2h[col];
                }
            }
            if (S + 1 < NSTEP) issueStep(S + 1, cur ^ 1);
            // Ledger: outstanding = S's 8 (oldest) [+ D 12 if cp==0] + S+1's 8.
            // cp==0: vmcnt(20) drains only S's 8 (D + S+1 stay in flight;
            //        D consumed at cp==3, compiler-waited, landed by then).
            // cp==1: vmcnt(8) drains D (full step of flight, free) + S's 8.
            // else : vmcnt(8) drains S's 8.
            if (S == NSTEP - 1)      asm volatile("s_waitcnt vmcnt(0)" ::: "memory");
            else if (cp == 0)        asm volatile("s_waitcnt vmcnt(20)" ::: "memory");
            else                     asm volatile("s_waitcnt vmcnt(8)" ::: "memory");
            __builtin_amdgcn_sched_barrier(0);      // rule 18

            #pragma unroll
            for (int j = 0; j < 2; ++j) {
                const int ch = cp * 2 + j;          // d-chunk 0..7, static
                #pragma unroll
                for (int n = 0; n < 4; ++n) {
                    f16x8 bh = *(const f16x8*)&lds[w][cur][n * 2 + j][lane * 8];
                    #pragma unroll
                    for (int m = 0; m < 2; ++m)
                        acc[m][n] = __builtin_amdgcn_mfma_f32_16x16x32_f16(ah[m][ch], bh, acc[m][n], 0, 0, 0);
                }
            }

            if (cp == 3) {   // per-kt epilogue: u = acc + row-code bound; top-2
                #pragma unroll
                for (int n = 0; n < 4; ++n) {
                    const int col = ktbase + h * 64 + n * 16 + c15;
                    #pragma unroll
                    for (int m = 0; m < 2; ++m)
                        #pragma unroll
                        for (int r = 0; r < 4; ++r) {
                            float u = fmaf(hnr[m][r], Dl[n],
                                      fmaf(rnr[m][r], Dc[n], acc[m][n][r] + D2[n]));
                            if (u > u1v[m][r]) { u2v[m][r] = u1v[m][r]; u1v[m][r] = u; u1i[m][r] = col; }
                            else if (u > u2v[m][r]) u2v[m][r] = u;
                            acc[m][n][r] = 0.f;
                        }
                }
            }
        }
    }

    // ---- merge top-2 across 16 c15-lanes, then across col-half waves ----
    __syncthreads();   // all staging/compute done; lds[0] = scratch (16 KB)
    float* sv1 = (float*)&lds[0][0][0][0];         // [row 0..63][half 0..1]
    int* si1 = (int*)((char*)&lds[0][0][0][0] + 1024);
    float* sv2 = (float*)((char*)&lds[0][0][0][0] + 2048);
    int* cand_s = (int*)((char*)&lds[0][0][0][0] + 4096);    // [64]
    float* thr_s = (float*)((char*)&lds[0][0][0][0] + 4608); // [64]
    #pragma unroll
    for (int m = 0; m < 2; ++m)
        #pragma unroll
        for (int r = 0; r < 4; ++r) {
            float a1 = u1v[m][r], a2 = u2v[m][r];
            int a1i = u1i[m][r];
            #pragma unroll
            for (int mask = 1; mask <= 8; mask <<= 1) {
                float b1 = __shfl_xor(a1, mask);
                int b1i = __shfl_xor(a1i, mask);
                float b2 = __shfl_xor(a2, mask);
                if (b1 > a1) { a2 = fmaxf(a1, b2); a1 = b1; a1i = b1i; }
                else         { a2 = fmaxf(b1, a2); }
            }
            if (c15 == 0) {
                const int rl = rh * 32 + m * 16 + g * 4 + r;   // 0..63
                sv1[rl * 2 + h] = a1;
                si1[rl * 2 + h] = a1i;
                sv2[rl * 2 + h] = a2;
            }
        }
    __syncthreads();
    if (t < 64) {
        float a1 = sv1[t * 2], a2 = sv2[t * 2];
        int a1i = si1[t * 2];
        float b1 = sv1[t * 2 + 1], b2 = sv2[t * 2 + 1];
        int b1i = si1[t * 2 + 1];
        float u1, u2; int u1idx;
        if (b1 > a1) { u1 = b1; u1idx = b1i; u2 = fmaxf(a1, b2); }
        else         { u1 = a1; u1idx = a1i; u2 = fmaxf(b1, a2); }
        cand_s[t] = u1idx;
        thr_s[t] = u2;
        out[brow + t] = u1idx;            // provisional; rescan may overwrite
    }
    __syncthreads();

    // ---- fused resolve: wave w exactly rescores rows w*16 .. w*16+15 ----
    #pragma unroll 1
    for (int i = 0; i < 16; ++i) {
        const int rl = w * 16 + i;
        const int grow = brow + rl;
        const int ci = cand_s[rl];
        const float4 rv = *(const float4*)(rep + (size_t)grow * DIM + lane * 4);
        const float4 cv = *(const float4*)(cb + (size_t)ci * DIM + lane * 4);
        float p = rv.x * cv.x + rv.y * cv.y + rv.z * cv.z + rv.w * cv.w;
        #pragma unroll
        for (int off = 32; off > 0; off >>= 1) p += __shfl_down(p, off);
        if (lane == 0) {
            float sex = p - c2h[ci];
            if (!(sex > thr_s[rl])) {     // not provably optimal -> rescan
                int pos = atomicAdd(cnt, 1);
                list[pos] = grow;
            }
        }
    }
}

// ---------------- rescan: (row-group x kt) parallel exact 4-pass tiles -------
__global__ __launch_bounds__(256) void rescan_kernel(
    const float* __restrict__ rep, const float* __restrict__ cb,
    const float* __restrict__ c2h, const int* __restrict__ cnt_p,
    const int* __restrict__ list, unsigned long long* __restrict__ keys) {

    const int cnt = *cnt_p;
    const int base = blockIdx.x * 64;
    if (base >= cnt) return;
    const int nrows = min(64, cnt - base);
    const int ktbase = (int)blockIdx.y * BN;

    __shared__ __align__(16) h16 lds[2][BN * 64];
    const int t = threadIdx.x;
    const int lane = t & 63;
    const int w = t >> 6;
    const int c15 = lane & 15;
    const int g = lane >> 4;
    const int wrow = w * 16;

    const int aslot = wrow + c15;
    const int grow = list[base + (aslot < nrows ? aslot : 0)];
    f16x8 ah[8], al[8];
    {
        const float* ar = rep + (size_t)grow * DIM + g * 8;
        #pragma unroll
        for (int ch = 0; ch < 8; ++ch) {
            float x[8];
            *(float4*)&x[0] = *(const float4*)(ar + ch * 32);
            *(float4*)&x[4] = *(const float4*)(ar + ch * 32 + 4);
            split8(x, ah[ch], al[ch]);
        }
    }
    f32x4 acc[8];
    float cc[8];
    #pragma unroll
    for (int n = 0; n < 8; ++n) {
        #pragma unroll
        for (int r = 0; r < 4; ++r) acc[n][r] = 0.f;
        cc[n] = c2h[ktbase + n * 16 + c15];
    }

    const int scol = t >> 1;
    const int dslot = t & 1;
    float breg[16];
    auto loadB = [&](int ch) {
        const float* src = cb + (size_t)(ktbase + scol) * DIM + ch * 32 + dslot * 16;
        #pragma unroll
        for (int i = 0; i < 4; ++i) *(float4*)&breg[i * 4] = *(const float4*)(src + i * 4);
    };
    auto writeB = [&](int buf) {
        #pragma unroll
        for (int half = 0; half < 2; ++half) {
            f16x8 hh, ll;
            split8(&breg[half * 8], hh, ll);
            const int s = dslot * 2 + half;
            *(f16x8*)&lds[buf][scol * 64 + ((s ^ (scol & 7)) << 3)] = hh;
            *(f16x8*)&lds[buf][scol * 64 + (((s + 4) ^ (scol & 7)) << 3)] = ll;
        }
    };

    loadB(0);
    writeB(0);
    loadB(1);
    __syncthreads();

    #pragma unroll
    for (int chunk = 0; chunk < 8; ++chunk) {
        const int buf = chunk & 1;
        if (chunk != 7) writeB(buf ^ 1);
        if (chunk <= 5) loadB(chunk + 2);
        #pragma unroll
        for (int n = 0; n < 8; ++n) {
            const int bb2 = (n * 16 + c15) * 64;
            f16x8 bh = *(const f16x8*)&lds[buf][bb2 + ((g ^ (lane & 7)) << 3)];
            f16x8 bl = *(const f16x8*)&lds[buf][bb2 + (((4 + g) ^ (lane & 7)) << 3)];
            acc[n] = __builtin_amdgcn_mfma_f32_16x16x32_f16(ah[chunk], bh, acc[n], 0, 0, 0);
            acc[n] = __builtin_amdgcn_mfma_f32_16x16x32_f16(ah[chunk], bl, acc[n], 0, 0, 0);
            acc[n] = __builtin_amdgcn_mfma_f32_16x16x32_f16(al[chunk], bh, acc[n], 0, 0, 0);
            acc[n] = __builtin_amdgcn_mfma_f32_16x16x32_f16(al[chunk], bl, acc[n], 0, 0, 0);
        }
        __syncthreads();
    }

    #pragma unroll
    for (int r = 0; r < 4; ++r) {
        float bv = -3.4e38f;
        int bi = 0;
        #pragma unroll
        for (int n = 0; n < 8; ++n) {
            float s2 = acc[n][r] - cc[n];
            const int col = ktbase + n * 16 + c15;
            if (s2 > bv) { bv = s2; bi = col; }
        }
        #pragma unroll
        for (int mask = 1; mask <= 8; mask <<= 1) {
            float ov = __shfl_xor(bv, mask);
            int oi = __shfl_xor(bi, mask);
            if (ov > bv || (ov == bv && oi < bi)) { bv = ov; bi = oi; }
        }
        const int oslot = wrow + g * 4 + r;
        if (c15 == 0 && oslot < nrows) {
            unsigned long long key =
                ((unsigned long long)ford(bv) << 32) | (unsigned int)(~(unsigned int)bi);
            atomicMax(&keys[list[base + oslot]], key);
        }
    }
}

// ---------------- writeback listed rows from merged keys ----------------
__global__ __launch_bounds__(256) void writeback_kernel(
    const int* __restrict__ cnt_p, const int* __restrict__ list,
    const unsigned long long* __restrict__ keys, int* __restrict__ out) {
    int i = blockIdx.x * 256 + threadIdx.x;
    if (i >= *cnt_p) return;
    int row = list[i];
    out[row] = (int)(~(unsigned int)(keys[row] & 0xFFFFFFFFull));
}

extern "C" void kernel_launch(void* const* d_in, const int* in_sizes, int n_in,
                              void* d_out, int out_size, void* d_ws, size_t ws_size,
                              hipStream_t stream) {
    const float* rep = (const float*)d_in[0];
    const float* cb = (const float*)d_in[1];
    const int N = in_sizes[0] / DIM;   // 65536
    const int K = in_sizes[1] / DIM;   // 8192
    (void)K;
    char* ws = (char*)d_ws;
    float* c2h = (float*)(ws + WS_C2H);
    float* lc  = (float*)(ws + WS_LC);
    float* cn  = (float*)(ws + WS_CN);
    int* cnt   = (int*)(ws + WS_CNT);
    int* list  = (int*)(ws + WS_LIST);
    unsigned long long* keys = (unsigned long long*)(ws + WS_KEYS);
    h16* Bph   = (h16*)(ws + WS_BPH);
    int* out = (int*)d_out;

    hipMemsetAsync(ws + WS_CNT, 0, 64, stream);
    hipMemsetAsync(keys, 0, (size_t)N * sizeof(unsigned long long), stream);
    prep_kernel<<<dim3(KCODES * 32 / 256), dim3(256), 0, stream>>>(cb, Bph, c2h, lc, cn);
    vq_pass1<<<dim3(N / 64), dim3(256), 0, stream>>>(rep, cb, Bph, c2h, lc, cn, out, cnt, list);
    rescan_kernel<<<dim3(N / 64, NKT), dim3(256), 0, stream>>>(rep, cb, c2h, cnt, list, keys);
    writeback_kernel<<<dim3(N / 256), dim3(256), 0, stream>>>(cnt, list, keys, out);
}